// Round 9
// baseline (223.612 us; speedup 1.0000x reference)
//
#include <hip/hip_runtime.h>

#define BB 4
#define NN 10000
#define MM 10000
#define PP 128
#define KS 32
#define KSC 4
#define ZZ 128

// workspace layout in floats (all offsets 16B-aligned)
#define OFF_PN 0                       // packed noisy  [B][N][4] (x,y,z,|p|^2)
#define OFF_PC (OFF_PN + BB*NN*4)      // packed clean  [B][M][4] (x,y,z,-|c|^2/2)
#define OFF_FO (OFF_PC + BB*MM*4)      // f_origin      [B][P][4]
#define OFF_ZP (OFF_FO + BB*PP*4)      // zpart         [B][P][128]
#define OFF_FP (OFF_ZP + BB*PP*ZZ)     // f points      [B][P][K][4]
#define OFF_GS (OFF_FP + BB*PP*KS*4)   // ground score  [B][P][K][4]
#define OFF_AC (OFF_GS + BB*PP*KS*4)   // loss accumulator [1]

#define FINF 1e30f

// ---------------- Stage 1: pack points; zero accumulator -----------------------
__global__ void k_pack(const float* __restrict__ noisy, const float* __restrict__ clean,
                       float* __restrict__ ws) {
    int t = blockIdx.x * blockDim.x + threadIdx.x;
    if (t == 0) ws[OFF_AC] = 0.0f;
    const int total = BB*NN + BB*MM;
    if (t >= total) return;
    if (t < BB*NN) {
        float x = noisy[t*3+0], y = noisy[t*3+1], z = noisy[t*3+2];
        float w = (x*x + y*y) + z*z;
        ((float4*)(ws + OFF_PN))[t] = make_float4(x, y, z, w);
    } else {
        int u = t - BB*NN;
        float x = clean[u*3+0], y = clean[u*3+1], z = clean[u*3+2];
        float w = -0.5f * ((x*x + y*y) + z*z);
        ((float4*)(ws + OFF_PC))[u] = make_float4(x, y, z, w);
    }
}

// ---------------- Stage 2: per sampled point: f_origin, feat MLP, zpart --------
__global__ void k_feat(const int* __restrict__ sidx,
                       const float* __restrict__ Wf1, const float* __restrict__ bf1,
                       const float* __restrict__ Wf2, const float* __restrict__ bf2,
                       const float* __restrict__ Ws1, const float* __restrict__ bs1,
                       float* __restrict__ ws) {
    int wave = (blockIdx.x * blockDim.x + threadIdx.x) >> 6;
    int lane = threadIdx.x & 63;
    if (wave >= BB*PP) return;
    int b = wave / PP, p = wave % PP;
    int si = sidx[p];
    float4 q = ((const float4*)(ws + OFF_PN))[b*NN + si];
    if (lane == 0) ((float4*)(ws + OFF_FO))[wave] = q;
    float h = bf1[lane];
    h = fmaf(q.x, Wf1[0*64 + lane], h);
    h = fmaf(q.y, Wf1[1*64 + lane], h);
    h = fmaf(q.z, Wf1[2*64 + lane], h);
    h = fmaxf(h, 0.0f);
    float fa = bf2[lane], fb = bf2[64 + lane];
    for (int i = 0; i < 64; ++i) {
        float hi = __shfl(h, i);
        fa = fmaf(hi, Wf2[i*ZZ + lane],      fa);
        fb = fmaf(hi, Wf2[i*ZZ + 64 + lane], fb);
    }
    float za = bs1[lane], zb = bs1[64 + lane];
    for (int i = 0; i < 64; ++i) {
        float va = __shfl(fa, i);
        float vb = __shfl(fb, i);
        za = fmaf(va, Ws1[(3 + i)*128 + lane],       za);
        zb = fmaf(va, Ws1[(3 + i)*128 + 64 + lane],  zb);
        za = fmaf(vb, Ws1[(67 + i)*128 + lane],      za);
        zb = fmaf(vb, Ws1[(67 + i)*128 + 64 + lane], zb);
    }
    ws[OFF_ZP + wave*ZZ + lane]      = za;
    ws[OFF_ZP + wave*ZZ + 64 + lane] = zb;
}

// ---------------- Stage 3: knn1 — block-per-query, 2-pass tau-gated ------------
#define CAP1 512
__global__ __launch_bounds__(256) void k_knn1(const int* __restrict__ sidx, float* __restrict__ ws) {
    __shared__ float cd[CAP1];
    __shared__ int   ci[CAP1];
    __shared__ float wtau[4];
    __shared__ int   cnt;
    int blk = blockIdx.x;               // global query id in [0,512)
    int b = blk >> 7, p = blk & 127;
    int tid = threadIdx.x;
    int w = tid >> 6, lane = tid & 63;
    const float4* pts = ((const float4*)(ws + OFF_PN)) + b*NN;
    float4 q = pts[sidx[p]];
    if (tid == 0) cnt = 0;
    float t0 = FINF, t1 = FINF;
    for (int j = tid; j < NN; j += 256) {
        float4 r = pts[j];
        float dot = fmaf(q.z, r.z, fmaf(q.y, r.y, q.x*r.x));
        float d = fmaf(dot, -2.0f, q.w + r.w);
        t1 = fminf(t1, fmaxf(t0, d));
        t0 = fminf(t0, d);
    }
    float m = 0.0f;
    for (int r = 0; r < KS; ++r) {
        m = t0;
        m = fminf(m, __shfl_xor(m, 1));
        m = fminf(m, __shfl_xor(m, 2));
        m = fminf(m, __shfl_xor(m, 4));
        m = fminf(m, __shfl_xor(m, 8));
        m = fminf(m, __shfl_xor(m, 16));
        m = fminf(m, __shfl_xor(m, 32));
        if (t0 == m) { t0 = t1; t1 = FINF; }
    }
    if (lane == 0) wtau[w] = m;
    __syncthreads();
    float tau = fminf(fminf(wtau[0], wtau[1]), fminf(wtau[2], wtau[3]));
    for (int j = tid; j < NN; j += 256) {
        float4 r = pts[j];
        float dot = fmaf(q.z, r.z, fmaf(q.y, r.y, q.x*r.x));
        float d = fmaf(dot, -2.0f, q.w + r.w);
        if (d <= tau) {
            int pos = atomicAdd(&cnt, 1);
            if (pos < CAP1) { cd[pos] = d; ci[pos] = j; }
        }
    }
    __syncthreads();
    int C = cnt; if (C > CAP1) C = CAP1;
    for (int i = tid; i < C; i += 256) {
        float di = cd[i]; int ii = ci[i];
        int rank = 0;
        for (int j2 = 0; j2 < C; ++j2) {
            float dj = cd[j2]; int ij = ci[j2];
            rank += ((dj < di) || (dj == di && ij < ii)) ? 1 : 0;
        }
        if (rank < KS) ((float4*)(ws + OFF_FP))[blk*KS + rank] = pts[ii];
    }
}

// ---------------- Stage 4: knn2 — append-list, batched ds_reads ----------------
// 512 blocks x 512 thr (8 waves), 32 queries/block. Lane = 8 subs x 8 qgroups,
// Q=4 queries/thread (named scalars). Wave w owns a 128-pt slice of each
// 1000-pt chunk (wave 7: 104 = 13x8, sub-uniform). Batches of 4: all 4
// ds_read_b128 issued BEFORE any gate/atomic (atomics block compiler hoisting
// of later reads -> source-level batching restores LDS pipelining).
// Phase A: branchless top-2/thread over chunks 0-1 -> tau (union-of-top-2
// subset => tau <= true 4th => gate e>=tau exact). Phase B: gated append.
// Phase C: exact (e desc, idx asc)-lex rank-select == jax stable top_k.
#define CHK2 1000
#define QPB 32
#define CAP2 128

#define K2Q(c) float fxv##c, fyv##c, fzv##c, tauv##c; \
    float ta0##c = -FINF, ta1##c = -FINF;

#define K2LOAD(c) { float4 f4_ = ((const float4*)(ws + OFF_FP))[qbase + qg*4 + c]; \
    fxv##c = f4_.x; fyv##c = f4_.y; fzv##c = f4_.z; }

#define AUPD(c, R) { float e_ = fmaf(fzv##c,(R).z,fmaf(fyv##c,(R).y,fmaf(fxv##c,(R).x,(R).w))); \
    ta1##c = fmaxf(ta1##c, fminf(ta0##c, e_)); ta0##c = fmaxf(ta0##c, e_); }

#define ASCAN(BUF) \
    for (int k_ = 0; k_ < kcnt; ++k_) { \
        float4 r_ = sp[BUF][sbase + k_*8 + sub]; \
        AUPD(0, r_) AUPD(1, r_) AUPD(2, r_) AUPD(3, r_) \
    }

#define AMRG(c) { \
    float h0_ = ta0##c, h1_ = ta1##c; \
    _Pragma("unroll") \
    for (int r_ = 0; r_ < 4; ++r_) { \
        float m_ = h0_; \
        m_ = fmaxf(m_, __shfl_xor(m_, 1)); \
        m_ = fmaxf(m_, __shfl_xor(m_, 2)); \
        m_ = fmaxf(m_, __shfl_xor(m_, 4)); \
        if (h0_ == m_) { h0_ = h1_; h1_ = -FINF; } \
        if (sub == r_) sWA[qg*4 + c][w*4 + r_] = m_; \
    } }

#define EVC(c, R) float ev##c = fmaf(fzv##c,(R).z,fmaf(fyv##c,(R).y,fmaf(fxv##c,(R).x,(R).w)));

#define APP(c) if (ev##c >= tauv##c) { \
    int pos_ = atomicAdd(&sCnt[qg*4 + c], 1); \
    if (pos_ < CAP2) { sCE[qg*4 + c][pos_] = ev##c; sCI[qg*4 + c][pos_] = gj_; } }

#define PROCP(J, KB, BASE) { \
    EVC(0, r##J) EVC(1, r##J) EVC(2, r##J) EVC(3, r##J) \
    float mx_ = fmaxf(fmaxf(ev0, ev1), fmaxf(ev2, ev3)); \
    if (mx_ >= cmin) { \
        int gj_ = (BASE) + sbase + (KB)*32 + (J)*8 + sub; \
        APP(0) APP(1) APP(2) APP(3) \
    } }

#define BATCH4(KB, BUF, BASE) { \
    float4 r0 = sp[BUF][sbase + (KB)*32 + 0*8 + sub]; \
    float4 r1 = sp[BUF][sbase + (KB)*32 + 1*8 + sub]; \
    float4 r2 = sp[BUF][sbase + (KB)*32 + 2*8 + sub]; \
    float4 r3 = sp[BUF][sbase + (KB)*32 + 3*8 + sub]; \
    PROCP(0, KB, BASE) PROCP(1, KB, BASE) PROCP(2, KB, BASE) PROCP(3, KB, BASE) }

#define BSCAN(BUF, BASE) \
    BATCH4(0, BUF, BASE) BATCH4(1, BUF, BASE) BATCH4(2, BUF, BASE) \
    if (w < 7) { BATCH4(3, BUF, BASE) } \
    else { \
        float4 r0 = sp[BUF][sbase + 96 + sub]; \
        PROCP(0, 3, BASE) \
    }

#define STAGE(BUF, CHUNK) \
    for (int u_ = tid; u_ < CHK2; u_ += 512) sp[BUF][u_] = pts[(CHUNK)*CHK2 + u_];

__global__ __launch_bounds__(512) void k_knn2(float* __restrict__ ws) {
    __shared__ float4 sp[2][CHK2];
    __shared__ float  sWA[QPB][33];
    __shared__ float  sCE[QPB][CAP2 + 1];
    __shared__ int    sCI[QPB][CAP2 + 1];
    __shared__ float  sTau[QPB];
    __shared__ int    sCnt[QPB];
    __shared__ int    sTop[QPB][4];
    int tid  = threadIdx.x;
    int w    = tid >> 6;                // 0..7
    int lane = tid & 63;
    int sub  = lane & 7;
    int qg   = lane >> 3;
    int qbase = blockIdx.x * QPB;
    int b = qbase >> 12;
    int sbase = w * 128;                // wave slice: 128 pts (wave 7: 104)
    int kcnt  = (w < 7) ? 16 : 13;
    const float4* pts = ((const float4*)(ws + OFF_PC)) + b*MM;

    K2Q(0) K2Q(1) K2Q(2) K2Q(3)
    K2LOAD(0) K2LOAD(1) K2LOAD(2) K2LOAD(3)
    if (tid < QPB) sCnt[tid] = 0;

    STAGE(0, 0)
    __syncthreads();
    STAGE(1, 1)                          // in flight under phase A on chunk 0

    // ---- phase A: sample = chunks 0+1 (branchless, pipelines freely) ----
    ASCAN(0)
    __syncthreads();                     // chunk 1 staged
    ASCAN(1)
    AMRG(0) AMRG(1) AMRG(2) AMRG(3)
    __syncthreads();
    if (tid < QPB) {
        float b0 = -FINF, b1 = -FINF, b2 = -FINF, b3 = -FINF;
        #pragma unroll
        for (int u = 0; u < 32; ++u) {
            float v = sWA[tid][u];
            b3 = fmaxf(b3, fminf(b2, v));
            b2 = fmaxf(b2, fminf(b1, v));
            b1 = fmaxf(b1, fminf(b0, v));
            b0 = fmaxf(b0, v);
        }
        sTau[tid] = b3;                  // 4th of union-of-top-2 <= true 4th
    }
    __syncthreads();
    tauv0 = sTau[qg*4 + 0]; tauv1 = sTau[qg*4 + 1];
    tauv2 = sTau[qg*4 + 2]; tauv3 = sTau[qg*4 + 3];
    float cmin = fminf(fminf(tauv0, tauv1), fminf(tauv2, tauv3));

    // ---- phase B: gated append scan over all 10 chunks (double-buffered) ----
    BSCAN(0, 0)
    __syncthreads();
    STAGE(0, 2) BSCAN(1, 1*CHK2)
    __syncthreads();
    STAGE(1, 3) BSCAN(0, 2*CHK2)
    __syncthreads();
    STAGE(0, 4) BSCAN(1, 3*CHK2)
    __syncthreads();
    STAGE(1, 5) BSCAN(0, 4*CHK2)
    __syncthreads();
    STAGE(0, 6) BSCAN(1, 5*CHK2)
    __syncthreads();
    STAGE(1, 7) BSCAN(0, 6*CHK2)
    __syncthreads();
    STAGE(0, 8) BSCAN(1, 7*CHK2)
    __syncthreads();
    STAGE(1, 9) BSCAN(0, 8*CHK2)
    __syncthreads();
    BSCAN(1, 9*CHK2)
    __syncthreads();

    // ---- phase C: exact lex rank-select (16 threads/query) ----
    {
        int qi = tid >> 4;
        int sl = tid & 15;
        int C = sCnt[qi]; if (C > CAP2) C = CAP2;
        for (int i = sl; i < C; i += 16) {
            float ei = sCE[qi][i]; int ii = sCI[qi][i];
            int rank = 0;
            for (int j = 0; j < C; ++j) {
                float ej = sCE[qi][j]; int ij = sCI[qi][j];
                rank += ((ej > ei) || (ej == ei && ij < ii)) ? 1 : 0;
            }
            if (rank < KSC) sTop[qi][rank] = ii;
        }
    }
    __syncthreads();
    if (tid < QPB) {
        int q = qbase + tid;
        float4 f4 = ((const float4*)(ws + OFF_FP))[q];
        float4 n0 = pts[sTop[tid][0]], n1 = pts[sTop[tid][1]];
        float4 n2 = pts[sTop[tid][2]], n3 = pts[sTop[tid][3]];
        float gx = 0.f, gy = 0.f, gz = 0.f;
        gx += n0.x - f4.x; gy += n0.y - f4.y; gz += n0.z - f4.z;
        gx += n1.x - f4.x; gy += n1.y - f4.y; gz += n1.z - f4.z;
        gx += n2.x - f4.x; gy += n2.y - f4.y; gz += n2.z - f4.z;
        gx += n3.x - f4.x; gy += n3.y - f4.y; gz += n3.z - f4.z;
        float* gsp = ws + OFF_GS + (size_t)q*4;
        gsp[0] = gx*0.25f; gsp[1] = gy*0.25f; gsp[2] = gz*0.25f;
    }
}

// ---------------- Stage 5: score MLP + loss — 4-wave j-split, packed g4 --------
__global__ __launch_bounds__(256) void k_mlp(const float* __restrict__ Ws1,
                                             const float* __restrict__ Ws2, const float* __restrict__ bs2,
                                             const float* __restrict__ Ws3, const float* __restrict__ bs3,
                                             float* __restrict__ ws) {
    __shared__ float4 sG[2][128];        // (zp_i, W1[0][i], W1[1][i], W1[2][i])
    __shared__ float4 sW2[128][16];
    __shared__ float  sB2[64];
    __shared__ float  sW3[64][3];
    __shared__ float  sB3[3];
    __shared__ float  sE[3][4][64];
    int tid = threadIdx.x;
    int w = tid >> 6, lane = tid & 63;
    for (int u = tid; u < 2048; u += 256) ((float4*)sW2)[u] = ((const float4*)Ws2)[u];
    if (tid < 64) sB2[tid] = bs2[tid];
    if (tid < 192) ((float*)sW3)[tid] = Ws3[tid];
    if (tid < 3) sB3[tid] = bs3[tid];
    {
        int grp = tid >> 7, i = tid & 127;
        sG[grp][i] = make_float4(ws[OFF_ZP + (blockIdx.x*2 + grp)*ZZ + i],
                                 Ws1[i], Ws1[128 + i], Ws1[256 + i]);
    }
    __syncthreads();

    int g = blockIdx.x*64 + lane;
    float4 f4 = ((const float4*)(ws + OFF_FP))[g];
    float4 fo = ((const float4*)(ws + OFF_FO))[g >> 5];
    float x0 = f4.x - fo.x, x1 = f4.y - fo.y, x2 = f4.z - fo.z;
    int grp = lane >> 5;

    float4 a[4];
    #pragma unroll
    for (int qq = 0; qq < 4; ++qq) a[qq] = make_float4(0.f, 0.f, 0.f, 0.f);
    for (int i = 0; i < 128; ++i) {
        float4 gv = sG[grp][i];
        float h1 = fmaf(x2, gv.w, fmaf(x1, gv.z, fmaf(x0, gv.y, gv.x)));
        h1 = fmaxf(h1, 0.0f);
        #pragma unroll
        for (int qq = 0; qq < 4; ++qq) {
            float4 wv = sW2[i][w*4 + qq];
            a[qq].x = fmaf(h1, wv.x, a[qq].x);
            a[qq].y = fmaf(h1, wv.y, a[qq].y);
            a[qq].z = fmaf(h1, wv.z, a[qq].z);
            a[qq].w = fmaf(h1, wv.w, a[qq].w);
        }
    }
    float p0 = 0.f, p1 = 0.f, p2 = 0.f;
    #pragma unroll
    for (int qq = 0; qq < 4; ++qq) {
        float av[4] = {a[qq].x, a[qq].y, a[qq].z, a[qq].w};
        #pragma unroll
        for (int cc = 0; cc < 4; ++cc) {
            int j = w*16 + qq*4 + cc;
            float h2 = fmaxf(av[cc] + sB2[j], 0.0f);
            p0 = fmaf(h2, sW3[j][0], p0);
            p1 = fmaf(h2, sW3[j][1], p1);
            p2 = fmaf(h2, sW3[j][2], p2);
        }
    }
    sE[0][w][lane] = p0; sE[1][w][lane] = p1; sE[2][w][lane] = p2;
    __syncthreads();
    if (w == 0) {
        float ee0 = ((sE[0][0][lane] + sE[0][1][lane]) + sE[0][2][lane]) + sE[0][3][lane] + sB3[0];
        float ee1 = ((sE[1][0][lane] + sE[1][1][lane]) + sE[1][2][lane]) + sE[1][3][lane] + sB3[1];
        float ee2 = ((sE[2][0][lane] + sE[2][1][lane]) + sE[2][2][lane]) + sE[2][3][lane] + sB3[2];
        const float* gsp = ws + OFF_GS + (size_t)g*4;
        float d0 = ee0 - gsp[0], d1 = ee1 - gsp[1], d2 = ee2 - gsp[2];
        float t = ((d0*d0 + d1*d1) + d2*d2) * 100.0f;
        for (int off = 32; off > 0; off >>= 1) t += __shfl_down(t, off);
        if (lane == 0) atomicAdd(ws + OFF_AC, t);
    }
}

// ---------------- Stage 6: finalize --------------------------------------------
__global__ void k_fin(const float* __restrict__ ws, float* __restrict__ out) {
    if (threadIdx.x == 0 && blockIdx.x == 0)
        out[0] = ws[OFF_AC] * (1.0f / 32768.0f);
}

extern "C" void kernel_launch(void* const* d_in, const int* in_sizes, int n_in,
                              void* d_out, int out_size, void* d_ws, size_t ws_size,
                              hipStream_t stream) {
    const float* noisy = (const float*)d_in[0];
    const float* clean = (const float*)d_in[1];
    const int*   sidx  = (const int*)  d_in[2];
    const float* Wf1 = (const float*)d_in[3];
    const float* bf1 = (const float*)d_in[4];
    const float* Wf2 = (const float*)d_in[5];
    const float* bf2 = (const float*)d_in[6];
    const float* Ws1 = (const float*)d_in[7];
    const float* bs1 = (const float*)d_in[8];
    const float* Ws2 = (const float*)d_in[9];
    const float* bs2 = (const float*)d_in[10];
    const float* Ws3 = (const float*)d_in[11];
    const float* bs3 = (const float*)d_in[12];
    float* ws  = (float*)d_ws;
    float* out = (float*)d_out;

    k_pack<<<(BB*NN + BB*MM + 255)/256, 256, 0, stream>>>(noisy, clean, ws);
    k_feat<<<(BB*PP*64)/256, 256, 0, stream>>>(sidx, Wf1, bf1, Wf2, bf2, Ws1, bs1, ws);
    k_knn1<<<BB*PP, 256, 0, stream>>>(sidx, ws);
    k_knn2<<<(BB*PP*KS)/QPB, 512, 0, stream>>>(ws);
    k_mlp<<<(BB*PP*KS)/64, 256, 0, stream>>>(Ws1, Ws2, bs2, Ws3, bs3, ws);
    k_fin<<<1, 64, 0, stream>>>(ws, out);
}